// Round 1
// baseline (104.520 us; speedup 1.0000x reference)
//
#include <hip/hip_runtime.h>

#define NF      39
#define ED      16
#define PAIRS   741
#define PADP    768          // padded pair count for ws layout
#define ROWPAD  20           // floats per row in LDS (5 float4s, odd -> bank spread)
#define SROW    (NF*ROWPAD)  // 780 floats per staged sample
#define SAMP    8            // samples per block
#define BATCH   8192
#define NBLK    (BATCH/SAMP) // 1024 blocks
#define F4_PER_SAMPLE (NF*ED/4)  // 156
#define EPS     1e-5f

// ---------------- pass 1: per-pair sums of inter and inter^2 -----------------
__global__ __launch_bounds__(256) void stats_k(
    const float* __restrict__ x, const int* __restrict__ rows,
    const int* __restrict__ cols, float* __restrict__ S1,
    float* __restrict__ S2, int repMask)
{
    __shared__ float lds[SAMP * SROW];   // ~25 KB
    const int t = threadIdx.x;
    const size_t base = (size_t)blockIdx.x * SAMP;
    const float4* xg = (const float4*)(x + base * (NF * ED));

    // stage 8 samples (1248 float4s) into LDS with padded row stride
    for (int u = t; u < SAMP * F4_PER_SAMPLE; u += 256) {
        int s = u / F4_PER_SAMPLE;
        int f = u - s * F4_PER_SAMPLE;     // float4 index within sample
        float4 v = xg[u];                  // fully coalesced
        *(float4*)&lds[s * SROW + (f >> 2) * ROWPAD + ((f & 3) << 2)] = v;
    }
    __syncthreads();

    const int r = blockIdx.x & repMask;    // replica set for atomics
    for (int p = t; p < PAIRS; p += 256) {
        const int ci = cols[p] * ROWPAD;
        const int rj = rows[p] * ROWPAD;
        float s1 = 0.f, s2 = 0.f;
        #pragma unroll
        for (int s = 0; s < SAMP; ++s) {
            const float4* A  = (const float4*)&lds[s * SROW + ci];
            const float4* Bv = (const float4*)&lds[s * SROW + rj];
            float v = 0.f;
            #pragma unroll
            for (int k = 0; k < 4; ++k) {
                float4 a = A[k], b = Bv[k];
                v = fmaf(a.x, b.x, v); v = fmaf(a.y, b.y, v);
                v = fmaf(a.z, b.z, v); v = fmaf(a.w, b.w, v);
            }
            s1 += v;
            s2 = fmaf(v, v, s2);
        }
        atomicAdd(&S1[r * PADP + p], s1);
        atomicAdd(&S2[r * PADP + p], s2);
    }
}

// -------- pass 2: fold stats into per-pair coeffs, weighted sum, output ------
__global__ __launch_bounds__(256) void out_k(
    const float* __restrict__ x, const float* __restrict__ ew,
    const float* __restrict__ gamma, const float* __restrict__ beta,
    const int* __restrict__ rows, const int* __restrict__ cols,
    const float* __restrict__ S1, const float* __restrict__ S2,
    float* __restrict__ out, int rep)
{
    __shared__ float lds[SAMP * SROW];
    __shared__ float cred[4];
    __shared__ float sred[4][SAMP];
    const int t = threadIdx.x;
    const size_t base = (size_t)blockIdx.x * SAMP;
    const float4* xg = (const float4*)(x + base * (NF * ED));

    for (int u = t; u < SAMP * F4_PER_SAMPLE; u += 256) {
        int s = u / F4_PER_SAMPLE;
        int f = u - s * F4_PER_SAMPLE;
        float4 v = xg[u];
        *(float4*)&lds[s * SROW + (f >> 2) * ROWPAD + ((f & 3) << 2)] = v;
    }
    __syncthreads();

    float wacc[SAMP];
    #pragma unroll
    for (int s = 0; s < SAMP; ++s) wacc[s] = 0.f;
    float cloc = 0.f;

    for (int p = t; p < PAIRS; p += 256) {
        const int ci = cols[p] * ROWPAD;
        const int rj = rows[p] * ROWPAD;

        // reconstruct stats for this pair (reads are L2-hot, tiny)
        float s1 = 0.f, s2 = 0.f;
        for (int r = 0; r < rep; ++r) {
            s1 += S1[r * PADP + p];
            s2 += S2[r * PADP + p];
        }
        const float mean = s1 * (1.f / BATCH);
        const float var  = fmaf(-mean, mean, s2 * (1.f / BATCH));
        const float rs   = 1.f / sqrtf(var + EPS);
        const float g    = gamma[p] * rs;
        const float w    = ew[p];
        const float a    = g * w;            // coefficient on inter
        cloc += (beta[p] - mean * g) * w;    // constant contribution

        #pragma unroll
        for (int s = 0; s < SAMP; ++s) {
            const float4* A  = (const float4*)&lds[s * SROW + ci];
            const float4* Bv = (const float4*)&lds[s * SROW + rj];
            float v = 0.f;
            #pragma unroll
            for (int k = 0; k < 4; ++k) {
                float4 a4 = A[k], b4 = Bv[k];
                v = fmaf(a4.x, b4.x, v); v = fmaf(a4.y, b4.y, v);
                v = fmaf(a4.z, b4.z, v); v = fmaf(a4.w, b4.w, v);
            }
            wacc[s] = fmaf(a, v, wacc[s]);
        }
    }

    // reduce cloc + wacc[8] across the 64-lane wave
    #pragma unroll
    for (int m = 32; m >= 1; m >>= 1) {
        cloc += __shfl_xor(cloc, m, 64);
        #pragma unroll
        for (int s = 0; s < SAMP; ++s) wacc[s] += __shfl_xor(wacc[s], m, 64);
    }
    const int wv = t >> 6, ln = t & 63;
    if (ln == 0) {
        cred[wv] = cloc;
        #pragma unroll
        for (int s = 0; s < SAMP; ++s) sred[wv][s] = wacc[s];
    }
    __syncthreads();
    if (t < SAMP) {
        float c = cred[0] + cred[1] + cred[2] + cred[3];
        float o = sred[0][t] + sred[1][t] + sred[2][t] + sred[3][t];
        out[base + t] = o + c;
    }
}

extern "C" void kernel_launch(void* const* d_in, const int* in_sizes, int n_in,
                              void* d_out, int out_size, void* d_ws, size_t ws_size,
                              hipStream_t stream)
{
    (void)in_sizes; (void)n_in; (void)out_size;
    const float* x     = (const float*)d_in[0];
    const float* ew    = (const float*)d_in[1];
    const float* gamma = (const float*)d_in[2];
    const float* beta  = (const float*)d_in[3];
    const int*   rows  = (const int*)d_in[4];
    const int*   cols  = (const int*)d_in[5];
    float* out = (float*)d_out;

    int rep = 8;  // replica sets for atomic-contention spreading
    while (rep > 1 && (size_t)(2 * rep * PADP * sizeof(float)) > ws_size) rep >>= 1;
    float* S1 = (float*)d_ws;
    float* S2 = S1 + rep * PADP;

    hipMemsetAsync(d_ws, 0, 2 * (size_t)rep * PADP * sizeof(float), stream);
    stats_k<<<NBLK, 256, 0, stream>>>(x, rows, cols, S1, S2, rep - 1);
    out_k<<<NBLK, 256, 0, stream>>>(x, ew, gamma, beta, rows, cols, S1, S2, out, rep);
}

// Round 5
// 104.250 us; speedup vs baseline: 1.0026x; 1.0026x over previous
//
#include <hip/hip_runtime.h>

#define NF      39
#define ED      16
#define PAIRS   741
#define PADP    768              // padded pair count for ws layout
#define ROWPAD  20               // floats per staged row (odd f4 stride -> bank spread)
#define SROW    (NF*ROWPAD)      // 780 floats per staged sample
#define IPAD    772              // ibuf row stride (772%32=4)
#define SAMP    8                // samples per block
#define BATCH   8192
#define NBLK    (BATCH/SAMP)     // 1024
#define F4S     (NF*ED/4)        // 156 float4 per sample
#define EPS     1e-5f
#define REP     8                // atomic replica sets

__device__ __forceinline__ float dot4(float4 a, float4 b) {
    float v = a.x * b.x;
    v = fmaf(a.y, b.y, v);
    v = fmaf(a.z, b.z, v);
    v = fmaf(a.w, b.w, v);
    return v;
}

// decode tile index (0..54) -> (tc, tr) in upper-triangle of 10x10 grid
__device__ __forceinline__ void tile_decode(int tile, int& tc, int& tr) {
    int rem = tile;
    tc = 0;
    while (rem >= 10 - tc) { rem -= 10 - tc; ++tc; }
    tr = tc + rem;
}

// compute the 4x4 dot tile for sample-base sb at tile (tc,tr)
__device__ __forceinline__ void tile_dots(const float* sb, int tc, int tr,
                                          float acc[4][4]) {
    int cOff[4], rOff[4];
    #pragma unroll
    for (int i = 0; i < 4; ++i) cOff[i] = min(4 * tc + i, NF - 1) * ROWPAD;
    #pragma unroll
    for (int j = 0; j < 4; ++j) rOff[j] = min(4 * tr + j, NF - 1) * ROWPAD;
    #pragma unroll
    for (int i = 0; i < 4; ++i)
        #pragma unroll
        for (int j = 0; j < 4; ++j) acc[i][j] = 0.f;
    // k-outer: only 8 float4 operands live at a time (low VGPR pressure)
    #pragma unroll
    for (int k = 0; k < 4; ++k) {
        float4 a[4], b[4];
        #pragma unroll
        for (int i = 0; i < 4; ++i) a[i] = *(const float4*)&sb[cOff[i] + 4 * k];
        #pragma unroll
        for (int j = 0; j < 4; ++j) b[j] = *(const float4*)&sb[rOff[j] + 4 * k];
        #pragma unroll
        for (int i = 0; i < 4; ++i)
            #pragma unroll
            for (int j = 0; j < 4; ++j)
                acc[i][j] += dot4(a[i], b[j]);
    }
}

// ---- pass 1: per-pair sums of inter and inter^2 (no inter materialization) ----
__global__ __launch_bounds__(256) void stats_k(
    const float* __restrict__ x, float* __restrict__ S1, float* __restrict__ S2)
{
    __shared__ float stage[SAMP * SROW];   // 24.96 KB
    __shared__ float ibuf[SAMP * IPAD];    // 24.7 KB
    const int t = threadIdx.x;
    const size_t base = (size_t)blockIdx.x * SAMP;
    const float4* xg = (const float4*)(x + base * (NF * ED));

    for (int u = t; u < SAMP * F4S; u += 256) {
        int s = u / F4S, f = u - s * F4S;
        float4 v = xg[u];
        *(float4*)&stage[s * SROW + (f >> 2) * ROWPAD + ((f & 3) << 2)] = v;
    }
    __syncthreads();

    for (int u = t; u < 55 * SAMP; u += 256) {
        const int s = u & 7;
        int tc, tr;
        tile_decode(u >> 3, tc, tr);
        float acc[4][4];
        tile_dots(&stage[s * SROW], tc, tr, acc);
        const int sbase = s * IPAD;
        #pragma unroll
        for (int i = 0; i < 4; ++i) {
            const int c = 4 * tc + i;
            const int pb = 38 * c - (c * (c - 1)) / 2 - c - 1;  // p = pb + r
            #pragma unroll
            for (int j = 0; j < 4; ++j) {
                const int r = 4 * tr + j;
                if (c < r && r < NF) ibuf[sbase + pb + r] = acc[i][j];
            }
        }
    }
    __syncthreads();

    // column-reduce the 8-sample tile -> replicated global atomics
    const int rp = (blockIdx.x & (REP - 1)) * PADP;
    for (int p = t; p < PAIRS; p += 256) {
        float s1 = 0.f, s2 = 0.f;
        #pragma unroll
        for (int s = 0; s < SAMP; ++s) {
            float v = ibuf[s * IPAD + p];
            s1 += v; s2 = fmaf(v, v, s2);
        }
        atomicAdd(&S1[rp + p], s1);
        atomicAdd(&S2[rp + p], s2);
    }
}

// ---- pass 2: per-block coef fold + dot recompute + weighted per-sample sum ----
__global__ __launch_bounds__(256) void out_k(
    const float* __restrict__ x, const float* __restrict__ S1,
    const float* __restrict__ S2, const float* __restrict__ ew,
    const float* __restrict__ gamma, const float* __restrict__ beta,
    float* __restrict__ out)
{
    __shared__ float stage[SAMP * SROW];   // 24.96 KB
    __shared__ float aS[PADP];             // 3 KB
    __shared__ float cred[4];
    __shared__ float sred[4][SAMP];
    const int t = threadIdx.x;
    const size_t base = (size_t)blockIdx.x * SAMP;
    const float4* xg = (const float4*)(x + base * (NF * ED));

    for (int u = t; u < SAMP * F4S; u += 256) {
        int s = u / F4S, f = u - s * F4S;
        float4 v = xg[u];
        *(float4*)&stage[s * SROW + (f >> 2) * ROWPAD + ((f & 3) << 2)] = v;
    }

    // fold stats into a[p] (LDS) and the scalar constant C
    float cl = 0.f;
    for (int p = t; p < PADP; p += 256) {
        float a = 0.f;
        if (p < PAIRS) {
            float s1 = 0.f, s2 = 0.f;
            #pragma unroll
            for (int r = 0; r < REP; ++r) {
                s1 += S1[r * PADP + p];
                s2 += S2[r * PADP + p];
            }
            const float mean = s1 * (1.f / BATCH);
            const float var  = fmaf(-mean, mean, s2 * (1.f / BATCH));
            const float g    = gamma[p] / sqrtf(var + EPS);
            const float w    = ew[p];
            a = w * g;
            cl = fmaf(beta[p] - mean * g, w, cl);
        }
        aS[p] = a;
    }
    #pragma unroll
    for (int m = 32; m; m >>= 1) cl += __shfl_xor(cl, m, 64);
    if ((t & 63) == 0) cred[t >> 6] = cl;
    __syncthreads();                       // covers stage, aS, cred
    const float Cv = cred[0] + cred[1] + cred[2] + cred[3];

    // each thread owns exactly one sample: s = t&7 (stride 256 == 0 mod 8)
    float wsum = 0.f;
    for (int u = t; u < 55 * SAMP; u += 256) {
        const int s = u & 7;
        int tc, tr;
        tile_decode(u >> 3, tc, tr);
        float acc[4][4];
        tile_dots(&stage[s * SROW], tc, tr, acc);
        #pragma unroll
        for (int i = 0; i < 4; ++i) {
            const int c = 4 * tc + i;
            const int pb = 38 * c - (c * (c - 1)) / 2 - c - 1;
            #pragma unroll
            for (int j = 0; j < 4; ++j) {
                const int r = 4 * tr + j;
                if (c < r && r < NF) wsum = fmaf(aS[pb + r], acc[i][j], wsum);
            }
        }
    }

    // reduce over the 8 lanes per wave sharing (lane&7), then across 4 waves
    #pragma unroll
    for (int m = 8; m < 64; m <<= 1) wsum += __shfl_xor(wsum, m, 64);
    if ((t & 63) < 8) sred[t >> 6][t & 7] = wsum;
    __syncthreads();
    if (t < SAMP) {
        out[base + t] = sred[0][t] + sred[1][t] + sred[2][t] + sred[3][t] + Cv;
    }
}

extern "C" void kernel_launch(void* const* d_in, const int* in_sizes, int n_in,
                              void* d_out, int out_size, void* d_ws, size_t ws_size,
                              hipStream_t stream)
{
    (void)in_sizes; (void)n_in; (void)out_size; (void)ws_size;
    const float* x     = (const float*)d_in[0];
    const float* ew    = (const float*)d_in[1];
    const float* gamma = (const float*)d_in[2];
    const float* beta  = (const float*)d_in[3];
    float* out = (float*)d_out;

    float* S1 = (float*)d_ws;              // REP*768
    float* S2 = S1 + REP * PADP;           // REP*768

    hipMemsetAsync(d_ws, 0, 2 * REP * PADP * sizeof(float), stream);
    stats_k<<<NBLK, 256, 0, stream>>>(x, S1, S2);
    out_k<<<NBLK, 256, 0, stream>>>(x, S1, S2, ew, gamma, beta, out);
}

// Round 7
// 102.633 us; speedup vs baseline: 1.0184x; 1.0158x over previous
//
#include <hip/hip_runtime.h>

#define NF      39
#define ED      16
#define PAIRS   741
#define PADP    768              // padded pair count for ws layout
#define ROWPAD  20               // floats per staged row (odd f4 stride -> bank spread)
#define SROW    (NF*ROWPAD)      // 780 floats per staged sample
#define IPAD    772              // ibuf row stride (772%32=4)
#define SAMP    8                // samples per block
#define BATCH   8192
#define NBLK    (BATCH/SAMP)     // 1024
#define F4S     (NF*ED/4)        // 156 float4 per sample
#define EPS     1e-5f
#define REP     8                // atomic replica sets

__device__ __forceinline__ float dot4(float4 a, float4 b) {
    float v = a.x * b.x;
    v = fmaf(a.y, b.y, v);
    v = fmaf(a.z, b.z, v);
    v = fmaf(a.w, b.w, v);
    return v;
}

// decode tile index (0..54) -> (tc, tr) in upper-triangle of 10x10 grid
__device__ __forceinline__ void tile_decode(int tile, int& tc, int& tr) {
    int rem = tile;
    tc = 0;
    while (rem >= 10 - tc) { rem -= 10 - tc; ++tc; }
    tr = tc + rem;
}

// compute the 4x4 dot tile for sample-base sb at tile (tc,tr)
__device__ __forceinline__ void tile_dots(const float* sb, int tc, int tr,
                                          float acc[4][4]) {
    int cOff[4], rOff[4];
    #pragma unroll
    for (int i = 0; i < 4; ++i) cOff[i] = min(4 * tc + i, NF - 1) * ROWPAD;
    #pragma unroll
    for (int j = 0; j < 4; ++j) rOff[j] = min(4 * tr + j, NF - 1) * ROWPAD;
    #pragma unroll
    for (int i = 0; i < 4; ++i)
        #pragma unroll
        for (int j = 0; j < 4; ++j) acc[i][j] = 0.f;
    // k-outer: only 8 float4 operands live at a time (low VGPR pressure)
    #pragma unroll
    for (int k = 0; k < 4; ++k) {
        float4 a[4], b[4];
        #pragma unroll
        for (int i = 0; i < 4; ++i) a[i] = *(const float4*)&sb[cOff[i] + 4 * k];
        #pragma unroll
        for (int j = 0; j < 4; ++j) b[j] = *(const float4*)&sb[rOff[j] + 4 * k];
        #pragma unroll
        for (int i = 0; i < 4; ++i)
            #pragma unroll
            for (int j = 0; j < 4; ++j)
                acc[i][j] += dot4(a[i], b[j]);
    }
}

// ---- pass 1: per-pair sums of inter and inter^2 (no inter materialization) ----
__global__ __launch_bounds__(256) void stats_k(
    const float* __restrict__ x, float* __restrict__ S1, float* __restrict__ S2)
{
    __shared__ float stage[SAMP * SROW];   // 24.96 KB
    __shared__ float ibuf[SAMP * IPAD];    // 24.7 KB
    const int t = threadIdx.x;
    const size_t base = (size_t)blockIdx.x * SAMP;
    const float4* xg = (const float4*)(x + base * (NF * ED));

    for (int u = t; u < SAMP * F4S; u += 256) {
        int s = u / F4S, f = u - s * F4S;
        float4 v = xg[u];
        *(float4*)&stage[s * SROW + (f >> 2) * ROWPAD + ((f & 3) << 2)] = v;
    }
    __syncthreads();

    for (int u = t; u < 55 * SAMP; u += 256) {
        const int s = u & 7;
        int tc, tr;
        tile_decode(u >> 3, tc, tr);
        float acc[4][4];
        tile_dots(&stage[s * SROW], tc, tr, acc);
        const int sbase = s * IPAD;
        #pragma unroll
        for (int i = 0; i < 4; ++i) {
            const int c = 4 * tc + i;
            const int pb = 38 * c - (c * (c - 1)) / 2 - c - 1;  // p = pb + r
            #pragma unroll
            for (int j = 0; j < 4; ++j) {
                const int r = 4 * tr + j;
                if (c < r && r < NF) ibuf[sbase + pb + r] = acc[i][j];
            }
        }
    }
    __syncthreads();

    // column-reduce the 8-sample tile -> replicated global atomics
    const int rp = (blockIdx.x & (REP - 1)) * PADP;
    for (int p = t; p < PAIRS; p += 256) {
        float s1 = 0.f, s2 = 0.f;
        #pragma unroll
        for (int s = 0; s < SAMP; ++s) {
            float v = ibuf[s * IPAD + p];
            s1 += v; s2 = fmaf(v, v, s2);
        }
        atomicAdd(&S1[rp + p], s1);
        atomicAdd(&S2[rp + p], s2);
    }
}

// ---- pass 2: per-block coef fold + dot recompute + weighted per-sample sum ----
__global__ __launch_bounds__(256) void out_k(
    const float* __restrict__ x, const float* __restrict__ S1,
    const float* __restrict__ S2, const float* __restrict__ ew,
    const float* __restrict__ gamma, const float* __restrict__ beta,
    float* __restrict__ out)
{
    __shared__ float stage[SAMP * SROW];   // 24.96 KB
    __shared__ float aS[PADP];             // 3 KB
    __shared__ float cred[4];
    __shared__ float sred[4][SAMP];
    const int t = threadIdx.x;
    const size_t base = (size_t)blockIdx.x * SAMP;
    const float4* xg = (const float4*)(x + base * (NF * ED));

    for (int u = t; u < SAMP * F4S; u += 256) {
        int s = u / F4S, f = u - s * F4S;
        float4 v = xg[u];
        *(float4*)&stage[s * SROW + (f >> 2) * ROWPAD + ((f & 3) << 2)] = v;
    }

    // fold stats into a[p] (LDS) and the scalar constant C
    float cl = 0.f;
    for (int p = t; p < PADP; p += 256) {
        float a = 0.f;
        if (p < PAIRS) {
            float s1 = 0.f, s2 = 0.f;
            #pragma unroll
            for (int r = 0; r < REP; ++r) {
                s1 += S1[r * PADP + p];
                s2 += S2[r * PADP + p];
            }
            const float mean = s1 * (1.f / BATCH);
            const float var  = fmaf(-mean, mean, s2 * (1.f / BATCH));
            const float g    = gamma[p] / sqrtf(var + EPS);
            const float w    = ew[p];
            a = w * g;
            cl = fmaf(beta[p] - mean * g, w, cl);
        }
        aS[p] = a;
    }
    #pragma unroll
    for (int m = 32; m; m >>= 1) cl += __shfl_xor(cl, m, 64);
    if ((t & 63) == 0) cred[t >> 6] = cl;
    __syncthreads();                       // covers stage, aS, cred
    const float Cv = cred[0] + cred[1] + cred[2] + cred[3];

    // each thread owns exactly one sample: s = t&7 (stride 256 == 0 mod 8)
    float wsum = 0.f;
    for (int u = t; u < 55 * SAMP; u += 256) {
        const int s = u & 7;
        int tc, tr;
        tile_decode(u >> 3, tc, tr);
        float acc[4][4];
        tile_dots(&stage[s * SROW], tc, tr, acc);
        #pragma unroll
        for (int i = 0; i < 4; ++i) {
            const int c = 4 * tc + i;
            const int pb = 38 * c - (c * (c - 1)) / 2 - c - 1;
            #pragma unroll
            for (int j = 0; j < 4; ++j) {
                const int r = 4 * tr + j;
                if (c < r && r < NF) wsum = fmaf(aS[pb + r], acc[i][j], wsum);
            }
        }
    }

    // reduce over the 8 lanes per wave sharing (lane&7), then across 4 waves
    #pragma unroll
    for (int m = 8; m < 64; m <<= 1) wsum += __shfl_xor(wsum, m, 64);
    if ((t & 63) < 8) sred[t >> 6][t & 7] = wsum;
    __syncthreads();
    if (t < SAMP) {
        out[base + t] = sred[0][t] + sred[1][t] + sred[2][t] + sred[3][t] + Cv;
    }
}

extern "C" void kernel_launch(void* const* d_in, const int* in_sizes, int n_in,
                              void* d_out, int out_size, void* d_ws, size_t ws_size,
                              hipStream_t stream)
{
    (void)in_sizes; (void)n_in; (void)out_size; (void)ws_size;
    const float* x     = (const float*)d_in[0];
    const float* ew    = (const float*)d_in[1];
    const float* gamma = (const float*)d_in[2];
    const float* beta  = (const float*)d_in[3];
    float* out = (float*)d_out;

    float* S1 = (float*)d_ws;              // REP*768
    float* S2 = S1 + REP * PADP;           // REP*768

    hipMemsetAsync(d_ws, 0, 2 * REP * PADP * sizeof(float), stream);
    stats_k<<<NBLK, 256, 0, stream>>>(x, S1, S2);
    out_k<<<NBLK, 256, 0, stream>>>(x, S1, S2, ew, gamma, beta, out);
}